// Round 5
// baseline (656.682 us; speedup 1.0000x reference)
//
#include <hip/hip_runtime.h>
#include <hip/hip_bf16.h>
#include <math.h>

#define BATCH   2
#define SEQLEN  2048
#define D_MODEL 1024
#define D_INNER 2048
#define D_STATE 16
#define NCHUNK  8
#define CHUNKT  256
#define NROW    (BATCH * SEQLEN)   // 4096
#define NCH     (BATCH * D_INNER)  // 4096 channels
#define EPSF    1e-10f

typedef unsigned short ushort_t;
typedef __attribute__((ext_vector_type(8))) short short8;
typedef __attribute__((ext_vector_type(4))) float f32x4;

__device__ __forceinline__ float bf2f(ushort_t u) {
    union { unsigned int i; float f; } v; v.i = ((unsigned int)u) << 16; return v.f;
}
__device__ __forceinline__ ushort_t f2bf(float f) {
    union { float f; unsigned int i; } v; v.f = f;
    unsigned int r = v.i + 0x7FFFu + ((v.i >> 16) & 1u);   // RNE
    return (ushort_t)(r >> 16);
}
__device__ __forceinline__ float frcp(float x) {
#if __has_builtin(__builtin_amdgcn_rcpf)
    return __builtin_amdgcn_rcpf(x);
#else
    return 1.0f / x;
#endif
}
__device__ __forceinline__ float softplus_f(float u) {
    return fmaxf(u, 0.f) + __logf(1.f + __expf(-fabsf(u)));
}

// DPP 16-lane row rotation (VALU pipe, replaces ds_swizzle shuffles).
// ror:1=0x121, ror:2=0x122, ror:4=0x124, ror:8=0x128.
template<int CTRL>
__device__ __forceinline__ float dpp_rot(float x) {
    union { float f; int i; } a, b;
    a.f = x;
    b.i = __builtin_amdgcn_update_dpp(0, a.i, CTRL, 0xF, 0xF, false);
    return b.f;
}
__device__ __forceinline__ float sum16(float x) {
    x += dpp_rot<0x121>(x);
    x += dpp_rot<0x122>(x);
    x += dpp_rot<0x124>(x);
    x += dpp_rot<0x128>(x);
    return x;   // every lane in the 16-group holds the 16-lane sum
}

// 8 contiguous elements -> bf16 short8 (for GEMM LDS staging)
__device__ __forceinline__ short8 ld8bf(const ushort_t* p) {
    return *(const short8*)p;
}
__device__ __forceinline__ short8 ld8bf(const float* p) {
    f32x4 a = ((const f32x4*)p)[0];
    f32x4 b = ((const f32x4*)p)[1];
    short8 r;
    r[0] = (short)f2bf(a[0]); r[1] = (short)f2bf(a[1]);
    r[2] = (short)f2bf(a[2]); r[3] = (short)f2bf(a[3]);
    r[4] = (short)f2bf(b[0]); r[5] = (short)f2bf(b[1]);
    r[6] = (short)f2bf(b[2]); r[7] = (short)f2bf(b[3]);
    return r;
}
__device__ __forceinline__ void st1(float* p, float v)    { *p = v; }
__device__ __forceinline__ void st1(ushort_t* p, float v) { *p = f2bf(v); }

// ---------------------------------------------------------------------------
// GEMM: C[M,N] = A[M,K] @ B[N,K]^T (unchanged — known correct).
// ---------------------------------------------------------------------------
template<int K, typename TA, typename TB, typename TC>
__global__ __launch_bounds__(256) void gemm_bt(const TA* __restrict__ A,
                                               const TB* __restrict__ B,
                                               TC* __restrict__ C, int N) {
    __shared__ alignas(16) ushort_t As[128][40];
    __shared__ alignas(16) ushort_t Bs[128][40];
    const int tid  = threadIdx.x;
    const int wave = tid >> 6, lane = tid & 63;
    const int wm = (wave >> 1) * 64, wn = (wave & 1) * 64;
    const int row0 = blockIdx.y * 128, col0 = blockIdx.x * 128;
    f32x4 acc[4][4] = {};
    const int srow = tid >> 2;
    const int sk   = (tid & 3) * 8;
    const int fr   = lane & 15;
    const int fk   = (lane >> 4) * 8;
    for (int k0 = 0; k0 < K; k0 += 32) {
        *(short8*)&As[srow][sk]      = ld8bf(&A[(size_t)(row0 + srow)      * K + k0 + sk]);
        *(short8*)&As[srow + 64][sk] = ld8bf(&A[(size_t)(row0 + srow + 64) * K + k0 + sk]);
        *(short8*)&Bs[srow][sk]      = ld8bf(&B[(size_t)(col0 + srow)      * K + k0 + sk]);
        *(short8*)&Bs[srow + 64][sk] = ld8bf(&B[(size_t)(col0 + srow + 64) * K + k0 + sk]);
        __syncthreads();
        short8 af[4], bfr[4];
        #pragma unroll
        for (int i = 0; i < 4; ++i) {
            af[i]  = *(const short8*)&As[wm + i * 16 + fr][fk];
            bfr[i] = *(const short8*)&Bs[wn + i * 16 + fr][fk];
        }
        #pragma unroll
        for (int i = 0; i < 4; ++i)
            #pragma unroll
            for (int j = 0; j < 4; ++j)
                acc[i][j] = __builtin_amdgcn_mfma_f32_16x16x32_bf16(af[i], bfr[j], acc[i][j], 0, 0, 0);
        __syncthreads();
    }
    const int quad = lane >> 4;
    #pragma unroll
    for (int i = 0; i < 4; ++i)
        #pragma unroll
        for (int j = 0; j < 4; ++j)
            #pragma unroll
            for (int r = 0; r < 4; ++r) {
                int row = row0 + wm + i * 16 + quad * 4 + r;
                int col = col0 + wn + j * 16 + fr;
                st1(&C[(size_t)row * N + col], acc[i][j][r]);
            }
}

// ---------------------------------------------------------------------------
// Depthwise causal conv (k=4) + bias + SiLU (unchanged).
// ---------------------------------------------------------------------------
__global__ __launch_bounds__(256) void conv_silu_k(const ushort_t* __restrict__ xz,
                                                   const float* __restrict__ cw,
                                                   const float* __restrict__ cb,
                                                   ushort_t* __restrict__ xc) {
    int idx = blockIdx.x * 256 + threadIdx.x;
    int d4  = (idx & (D_INNER / 4 - 1)) * 4;
    int row = idx >> 9;
    int t   = row & (SEQLEN - 1);
    float a[4] = {0.f, 0.f, 0.f, 0.f};
    #pragma unroll
    for (int j = 0; j < 4; ++j) {
        int tt = t - 3 + j;
        if (tt >= 0) {
            const ushort_t* p = &xz[(size_t)(row - 3 + j) * (2 * D_INNER) + d4];
            #pragma unroll
            for (int u = 0; u < 4; ++u)
                a[u] += cw[(d4 + u) * 4 + j] * bf2f(p[u]);
        }
    }
    #pragma unroll
    for (int u = 0; u < 4; ++u) {
        float v  = a[u] + cb[d4 + u];
        float sv = v / (1.f + expf(-v));
        xc[(size_t)row * D_INNER + d4 + u] = f2bf(sv);
    }
}

// ---------------------------------------------------------------------------
// x_proj: xp_T[j, row] = xc[row,:] . x_proj_w[j,:]  (TRANSPOSED store so the
// scan reads B/C/xp0 contiguously along t).
// ---------------------------------------------------------------------------
__global__ __launch_bounds__(256) void xproj_k(const ushort_t* __restrict__ xc,
                                               const float* __restrict__ w,
                                               float* __restrict__ xp_T) {
    int row  = blockIdx.x * 4 + (threadIdx.x >> 6);
    int lane = threadIdx.x & 63;
    const ushort_t* xr = xc + (size_t)row * D_INNER;
    float xf[32];
    #pragma unroll
    for (int c = 0; c < 4; ++c) {
        short8 xv = *(const short8*)&xr[c * 512 + lane * 8];
        #pragma unroll
        for (int u = 0; u < 8; ++u) xf[c * 8 + u] = bf2f((ushort_t)xv[u]);
    }
    for (int j = 0; j < 33; ++j) {
        float acc = 0.f;
        #pragma unroll
        for (int c = 0; c < 4; ++c) {
            const f32x4* wp = (const f32x4*)&w[(size_t)j * D_INNER + c * 512 + lane * 8];
            f32x4 w0 = wp[0], w1 = wp[1];
            #pragma unroll
            for (int u = 0; u < 4; ++u) acc += xf[c * 8 + u]     * w0[u];
            #pragma unroll
            for (int u = 0; u < 4; ++u) acc += xf[c * 8 + 4 + u] * w1[u];
        }
        acc += __shfl_xor(acc, 32); acc += __shfl_xor(acc, 16);
        acc += __shfl_xor(acc, 8);  acc += __shfl_xor(acc, 4);
        acc += __shfl_xor(acc, 2);  acc += __shfl_xor(acc, 1);
        if (lane == 0) xp_T[(size_t)j * NROW + row] = acc;
    }
}

// ---------------------------------------------------------------------------
// NEW: transpose xc[row, d] (bf16) -> xc_T[b*D_INNER+d, t] so the scan's
// per-channel walk along t is contiguous.  64x64 LDS tiles; scattered u16
// LDS writes (<=2-way bank alias), contiguous short8 LDS reads + stores.
// ---------------------------------------------------------------------------
__global__ __launch_bounds__(256) void transpose_k(const ushort_t* __restrict__ xc,
                                                   ushort_t* __restrict__ xc_T) {
    __shared__ ushort_t tileT[64][65];
    const int tid = threadIdx.x;
    const int t0 = blockIdx.x * 64, d0 = blockIdx.y * 64, b = blockIdx.z;
    const int dl = (tid & 7) * 8;
    const int tl = tid >> 3;                      // 0..31
    #pragma unroll
    for (int it = 0; it < 2; ++it) {
        const int tt = tl + it * 32;
        short8 v = *(const short8*)&xc[(size_t)(b * SEQLEN + t0 + tt) * D_INNER + d0 + dl];
        #pragma unroll
        for (int k = 0; k < 8; ++k) tileT[dl + k][tt] = (ushort_t)v[k];
    }
    __syncthreads();
    const int tl2 = (tid & 7) * 8;
    const int dl2 = tid >> 3;                     // 0..31
    #pragma unroll
    for (int it = 0; it < 2; ++it) {
        const int dd = dl2 + it * 32;
        short8 w = *(const short8*)&tileT[dd][tl2];
        *(short8*)&xc_T[(size_t)(b * D_INNER + d0 + dd) * SEQLEN + t0 + tl2] = w;
    }
}

// ---------------------------------------------------------------------------
// Chunk-parallel selective scan, time-major reads.  Per-chunk recurrence is
// affine in entering state h0: h_end = P*h0 + q.  delta recomputed inline
// (bitwise-identical formula to the round-3/4 passing kernels).
// Lane = (channel, state): 4 channels x 16 states per wave.
// ---------------------------------------------------------------------------
__global__ __launch_bounds__(256) void scan_p1(const ushort_t* __restrict__ xc_T,
                                               const float* __restrict__ xp_T,
                                               const float* __restrict__ dt_w,
                                               const float* __restrict__ dt_b,
                                               const float* __restrict__ A_log,
                                               float* __restrict__ Pbuf,
                                               float* __restrict__ qbuf) {
    const int tid = threadIdx.x;
    const int s   = tid & 15;
    const int ch  = blockIdx.x * 16 + (tid >> 4);
    const int c   = blockIdx.y;
    const int b   = ch >> 11;
    const int d   = ch & (D_INNER - 1);
    const float A_s = -__expf(A_log[s]);
    const float dtw = dt_w[d];
    const float dtb = dt_b[d];
    const int rowbase = b * SEQLEN + c * CHUNKT;
    const ushort_t* xcp = xc_T + (size_t)ch * SEQLEN + c * CHUNKT;
    const float*    p0p = xp_T + rowbase;                       // j = 0
    const float*    Bp  = xp_T + (size_t)(1 + s) * NROW + rowbase;
    float Acum = 1.f, wc = 0.f, prevA = 1.f;
    for (int T = 0; T < CHUNKT; T += 8) {
        const short8 xv = *(const short8*)xcp;
        const f32x4 p0a = ((const f32x4*)p0p)[0], p0b = ((const f32x4*)p0p)[1];
        const f32x4 Ba  = ((const f32x4*)Bp)[0],  Bb  = ((const f32x4*)Bp)[1];
        #pragma unroll
        for (int k = 0; k < 8; ++k) {
            const float xp0 = (k < 4) ? p0a[k] : p0b[k - 4];
            const float Bv  = (k < 4) ? Ba[k]  : Bb[k - 4];
            const float xcv = bf2f((ushort_t)xv[k]);
            const float dv  = softplus_f(fmaf(xp0, dtw, dtb));
            const float Ab  = fmaxf(__expf(dv * A_s), EPSF);
            prevA = Acum;
            Acum  = prevA * Ab;
            wc    = fmaf(dv * Bv * xcv, frcp(fmaxf(prevA, EPSF)), wc);
        }
        xcp += 8; p0p += 8; Bp += 8;
    }
    const size_t base = ((size_t)c * NCH + ch) * 16 + s;
    Pbuf[base] = Acum;
    qbuf[base] = prevA * wc;
}

__global__ __launch_bounds__(256) void combine_k(const float* __restrict__ Pbuf,
                                                 const float* __restrict__ qbuf,
                                                 float* __restrict__ hbuf) {
    const int i = blockIdx.x * 256 + threadIdx.x;
    float h = 0.f;
    #pragma unroll
    for (int c = 0; c < NCHUNK; ++c) {
        const size_t idx = (size_t)c * (NCH * 16) + i;
        hbuf[idx] = h;                               // state ENTERING chunk c
        h = fmaf(Pbuf[idx], h, qbuf[idx]);
    }
}

__global__ __launch_bounds__(256) void scan_p2(const ushort_t* __restrict__ xc_T,
                                               const float* __restrict__ xp_T,
                                               const ushort_t* __restrict__ xz,
                                               const float* __restrict__ dt_w,
                                               const float* __restrict__ dt_b,
                                               const float* __restrict__ A_log,
                                               const float* __restrict__ D_par,
                                               const float* __restrict__ hbuf,
                                               ushort_t* __restrict__ G) {
    const int tid = threadIdx.x;
    const int s   = tid & 15;
    const int ch  = blockIdx.x * 16 + (tid >> 4);
    const int c   = blockIdx.y;
    const int b   = ch >> 11;
    const int d   = ch & (D_INNER - 1);
    const float A_s = -__expf(A_log[s]);
    const float dtw = dt_w[d];
    const float dtb = dt_b[d];
    const float Dp  = D_par[d];
    const float h0  = hbuf[((size_t)c * NCH + ch) * 16 + s];
    const int rowbase = b * SEQLEN + c * CHUNKT;
    const ushort_t* xcp = xc_T + (size_t)ch * SEQLEN + c * CHUNKT;
    const float*    p0p = xp_T + rowbase;
    const float*    Bp  = xp_T + (size_t)(1 + s) * NROW + rowbase;
    const float*    Cp  = xp_T + (size_t)(17 + s) * NROW + rowbase;
    const ushort_t* zp  = xz + (size_t)rowbase * (2 * D_INNER) + D_INNER + d;
    ushort_t*       Gp  = G  + (size_t)rowbase * D_INNER + d;
    float Acum = 1.f, wc = 0.f;
    for (int T = 0; T < CHUNKT; T += 8) {
        const short8 xv = *(const short8*)xcp;
        const f32x4 p0a = ((const f32x4*)p0p)[0], p0b = ((const f32x4*)p0p)[1];
        const f32x4 Ba  = ((const f32x4*)Bp)[0],  Bb  = ((const f32x4*)Bp)[1];
        const f32x4 Ca  = ((const f32x4*)Cp)[0],  Cb  = ((const f32x4*)Cp)[1];
        float zf[8];
        #pragma unroll
        for (int k = 0; k < 8; ++k) zf[k] = bf2f(zp[(size_t)k * (2 * D_INNER)]);
        #pragma unroll
        for (int k = 0; k < 8; ++k) {
            const float xp0 = (k < 4) ? p0a[k] : p0b[k - 4];
            const float Bv  = (k < 4) ? Ba[k]  : Bb[k - 4];
            const float Cv  = (k < 4) ? Ca[k]  : Cb[k - 4];
            const float xcv = bf2f((ushort_t)xv[k]);
            const float dv  = softplus_f(fmaf(xp0, dtw, dtb));
            const float Ab  = fmaxf(__expf(dv * A_s), EPSF);
            const float prevA = Acum;
            Acum = prevA * Ab;
            wc   = fmaf(dv * Bv * xcv, frcp(fmaxf(prevA, EPSF)), wc);
            const float h  = fmaf(prevA, wc, h0 * Acum);
            const float ys = sum16(Cv * h);
            if (s == 0) {
                const float z = zf[k];
                const float y = fmaf(Dp, xcv, ys);
                Gp[(size_t)k * D_INNER] = f2bf(y * z * frcp(1.f + __expf(-z)));
            }
        }
        xcp += 8; p0p += 8; Bp += 8; Cp += 8;
        zp += 8 * (2 * D_INNER); Gp += 8 * D_INNER;
    }
}

// ---------------------------------------------------------------------------
extern "C" void kernel_launch(void* const* d_in, const int* in_sizes, int n_in,
                              void* d_out, int out_size, void* d_ws, size_t ws_size,
                              hipStream_t stream) {
    const float* x     = (const float*)d_in[0];
    const float* w_in  = (const float*)d_in[1];
    const float* cw    = (const float*)d_in[2];
    const float* cb    = (const float*)d_in[3];
    const float* w_xp  = (const float*)d_in[4];
    const float* dtw   = (const float*)d_in[5];
    const float* dtb   = (const float*)d_in[6];
    const float* alog  = (const float*)d_in[7];
    const float* dpar  = (const float*)d_in[8];
    const float* w_out = (const float*)d_in[9];
    float* out = (float*)d_out;

    char* ws = (char*)d_ws;
    const size_t MB = 1024ull * 1024ull;
    ushort_t* xz   = (ushort_t*)ws;                  // 32 MiB (xi|z), alive throughout
    ushort_t* xc   = (ushort_t*)(ws + 32 * MB);      // 16 MiB row-major; G overlays later
    float*    xp_T = (float*)   (ws + 48 * MB);      // 0.54 MiB [33, NROW]
    float*    Pbuf = (float*)   (ws + 49 * MB);      // 2 MiB
    float*    qbuf = (float*)   (ws + 51 * MB);      // 2 MiB
    float*    hbuf = (float*)   (ws + 53 * MB);      // 2 MiB
    ushort_t* xcT  = (ushort_t*)(ws + 55 * MB);      // 16 MiB [NCH, SEQLEN]  (total 71 MiB)
    ushort_t* G    = xc;                             // in-place over xc (dead after xproj+transpose)

    // 1) xz = x @ in_proj_w^T   (M=4096, N=4096, K=1024)
    hipLaunchKernelGGL((gemm_bt<D_MODEL, float, float, ushort_t>),
                       dim3(2 * D_INNER / 128, NROW / 128), dim3(256), 0, stream,
                       x, w_in, xz, 2 * D_INNER);
    // 2) xc = silu(causal depthwise conv(xi) + cb)
    hipLaunchKernelGGL(conv_silu_k, dim3(NROW * (D_INNER / 4) / 256), dim3(256), 0, stream,
                       xz, cw, cb, xc);
    // 3) xp_T = (xc @ x_proj_w^T)^T
    hipLaunchKernelGGL(xproj_k, dim3(NROW / 4), dim3(256), 0, stream, xc, w_xp, xp_T);
    // 3b) xc -> xc_T (time-major for the scan)
    hipLaunchKernelGGL(transpose_k, dim3(SEQLEN / 64, D_INNER / 64, BATCH), dim3(256), 0, stream,
                       xc, xcT);
    // 4a) per-chunk (P,q)
    hipLaunchKernelGGL(scan_p1, dim3(NCH / 16, NCHUNK), dim3(256), 0, stream,
                       xcT, xp_T, dtw, dtb, alog, Pbuf, qbuf);
    // 4b) chunk chain -> h0 per chunk
    hipLaunchKernelGGL(combine_k, dim3(NCH * 16 / 256), dim3(256), 0, stream,
                       Pbuf, qbuf, hbuf);
    // 4c) replay with h0, emit G = (C.h + D*x)*silu(z)  (in place over xc)
    hipLaunchKernelGGL(scan_p2, dim3(NCH / 16, NCHUNK), dim3(256), 0, stream,
                       xcT, xp_T, xz, dtw, dtb, alog, dpar, hbuf, G);
    // 5) out = G @ out_proj_w^T  (M=4096, N=1024, K=2048)
    hipLaunchKernelGGL((gemm_bt<D_INNER, ushort_t, float, float>),
                       dim3(D_MODEL / 128, NROW / 128), dim3(256), 0, stream,
                       G, w_out, out, D_MODEL);
    (void)in_sizes; (void)n_in; (void)out_size; (void)ws_size;
}

// Round 6
// 586.191 us; speedup vs baseline: 1.1203x; 1.1203x over previous
//
#include <hip/hip_runtime.h>
#include <hip/hip_bf16.h>
#include <math.h>

#define BATCH   2
#define SEQLEN  2048
#define D_MODEL 1024
#define D_INNER 2048
#define D_STATE 16
#define NCHUNK  8
#define CHUNKT  256
#define NROW    (BATCH * SEQLEN)   // 4096
#define NCH     (BATCH * D_INNER)  // 4096 channels
#define EPSF    1e-10f

typedef unsigned short ushort_t;
typedef __attribute__((ext_vector_type(8))) short short8;
typedef __attribute__((ext_vector_type(4))) float f32x4;

__device__ __forceinline__ float bf2f(ushort_t u) {
    union { unsigned int i; float f; } v; v.i = ((unsigned int)u) << 16; return v.f;
}
__device__ __forceinline__ ushort_t f2bf(float f) {
    union { float f; unsigned int i; } v; v.f = f;
    unsigned int r = v.i + 0x7FFFu + ((v.i >> 16) & 1u);   // RNE
    return (ushort_t)(r >> 16);
}
__device__ __forceinline__ float frcp(float x) {
#if __has_builtin(__builtin_amdgcn_rcpf)
    return __builtin_amdgcn_rcpf(x);
#else
    return 1.0f / x;
#endif
}
__device__ __forceinline__ float softplus_f(float u) {
    return fmaxf(u, 0.f) + __logf(1.f + __expf(-fabsf(u)));
}

// ds_swizzle broadcast: every lane in its 16-group receives lane K's value.
// BitMode: new_lane = ((lane & 0x10) | K)  -> offset = (K<<5) | 0x10.
template<int K16>
__device__ __forceinline__ float bcast16(float x) {
    union { float f; int i; } a, b; a.f = x;
    b.i = __builtin_amdgcn_ds_swizzle(a.i, (K16 << 5) | 0x10);
    return b.f;
}
// xor-butterfly add within 16-group (DS pipe): offset = (MASK<<10) | 0x1F.
template<int MASK>
__device__ __forceinline__ float swz_add(float x) {
    union { float f; int i; } a, b; a.f = x;
    b.i = __builtin_amdgcn_ds_swizzle(a.i, (MASK << 10) | 0x1F);
    return x + b.f;
}
__device__ __forceinline__ float sum16(float x) {
    x = swz_add<1>(x); x = swz_add<2>(x); x = swz_add<4>(x); x = swz_add<8>(x);
    return x;   // all 16 lanes hold the group sum
}

// 8 contiguous elements -> bf16 short8 (for GEMM LDS staging)
__device__ __forceinline__ short8 ld8bf(const ushort_t* p) {
    return *(const short8*)p;
}
__device__ __forceinline__ short8 ld8bf(const float* p) {
    f32x4 a = ((const f32x4*)p)[0];
    f32x4 b = ((const f32x4*)p)[1];
    short8 r;
    r[0] = (short)f2bf(a[0]); r[1] = (short)f2bf(a[1]);
    r[2] = (short)f2bf(a[2]); r[3] = (short)f2bf(a[3]);
    r[4] = (short)f2bf(b[0]); r[5] = (short)f2bf(b[1]);
    r[6] = (short)f2bf(b[2]); r[7] = (short)f2bf(b[3]);
    return r;
}
__device__ __forceinline__ void st1(float* p, float v)    { *p = v; }
__device__ __forceinline__ void st1(ushort_t* p, float v) { *p = f2bf(v); }

// ---------------------------------------------------------------------------
// GEMM: C[M,N] = A[M,K] @ B[N,K]^T (unchanged — known correct).
// ---------------------------------------------------------------------------
template<int K, typename TA, typename TB, typename TC>
__global__ __launch_bounds__(256) void gemm_bt(const TA* __restrict__ A,
                                               const TB* __restrict__ B,
                                               TC* __restrict__ C, int N) {
    __shared__ alignas(16) ushort_t As[128][40];
    __shared__ alignas(16) ushort_t Bs[128][40];
    const int tid  = threadIdx.x;
    const int wave = tid >> 6, lane = tid & 63;
    const int wm = (wave >> 1) * 64, wn = (wave & 1) * 64;
    const int row0 = blockIdx.y * 128, col0 = blockIdx.x * 128;
    f32x4 acc[4][4] = {};
    const int srow = tid >> 2;
    const int sk   = (tid & 3) * 8;
    const int fr   = lane & 15;
    const int fk   = (lane >> 4) * 8;
    for (int k0 = 0; k0 < K; k0 += 32) {
        *(short8*)&As[srow][sk]      = ld8bf(&A[(size_t)(row0 + srow)      * K + k0 + sk]);
        *(short8*)&As[srow + 64][sk] = ld8bf(&A[(size_t)(row0 + srow + 64) * K + k0 + sk]);
        *(short8*)&Bs[srow][sk]      = ld8bf(&B[(size_t)(col0 + srow)      * K + k0 + sk]);
        *(short8*)&Bs[srow + 64][sk] = ld8bf(&B[(size_t)(col0 + srow + 64) * K + k0 + sk]);
        __syncthreads();
        short8 af[4], bfr[4];
        #pragma unroll
        for (int i = 0; i < 4; ++i) {
            af[i]  = *(const short8*)&As[wm + i * 16 + fr][fk];
            bfr[i] = *(const short8*)&Bs[wn + i * 16 + fr][fk];
        }
        #pragma unroll
        for (int i = 0; i < 4; ++i)
            #pragma unroll
            for (int j = 0; j < 4; ++j)
                acc[i][j] = __builtin_amdgcn_mfma_f32_16x16x32_bf16(af[i], bfr[j], acc[i][j], 0, 0, 0);
        __syncthreads();
    }
    const int quad = lane >> 4;
    #pragma unroll
    for (int i = 0; i < 4; ++i)
        #pragma unroll
        for (int j = 0; j < 4; ++j)
            #pragma unroll
            for (int r = 0; r < 4; ++r) {
                int row = row0 + wm + i * 16 + quad * 4 + r;
                int col = col0 + wn + j * 16 + fr;
                st1(&C[(size_t)row * N + col], acc[i][j][r]);
            }
}

// ---------------------------------------------------------------------------
// Depthwise causal conv (k=4) + bias + SiLU (unchanged).
// ---------------------------------------------------------------------------
__global__ __launch_bounds__(256) void conv_silu_k(const ushort_t* __restrict__ xz,
                                                   const float* __restrict__ cw,
                                                   const float* __restrict__ cb,
                                                   ushort_t* __restrict__ xc) {
    int idx = blockIdx.x * 256 + threadIdx.x;
    int d4  = (idx & (D_INNER / 4 - 1)) * 4;
    int row = idx >> 9;
    int t   = row & (SEQLEN - 1);
    float a[4] = {0.f, 0.f, 0.f, 0.f};
    #pragma unroll
    for (int j = 0; j < 4; ++j) {
        int tt = t - 3 + j;
        if (tt >= 0) {
            const ushort_t* p = &xz[(size_t)(row - 3 + j) * (2 * D_INNER) + d4];
            #pragma unroll
            for (int u = 0; u < 4; ++u)
                a[u] += cw[(d4 + u) * 4 + j] * bf2f(p[u]);
        }
    }
    #pragma unroll
    for (int u = 0; u < 4; ++u) {
        float v  = a[u] + cb[d4 + u];
        float sv = v / (1.f + expf(-v));
        xc[(size_t)row * D_INNER + d4 + u] = f2bf(sv);
    }
}

// ---------------------------------------------------------------------------
// x_proj: xp_T[j, row] (transposed store; unchanged from round 5).
// ---------------------------------------------------------------------------
__global__ __launch_bounds__(256) void xproj_k(const ushort_t* __restrict__ xc,
                                               const float* __restrict__ w,
                                               float* __restrict__ xp_T) {
    int row  = blockIdx.x * 4 + (threadIdx.x >> 6);
    int lane = threadIdx.x & 63;
    const ushort_t* xr = xc + (size_t)row * D_INNER;
    float xf[32];
    #pragma unroll
    for (int c = 0; c < 4; ++c) {
        short8 xv = *(const short8*)&xr[c * 512 + lane * 8];
        #pragma unroll
        for (int u = 0; u < 8; ++u) xf[c * 8 + u] = bf2f((ushort_t)xv[u]);
    }
    for (int j = 0; j < 33; ++j) {
        float acc = 0.f;
        #pragma unroll
        for (int c = 0; c < 4; ++c) {
            const f32x4* wp = (const f32x4*)&w[(size_t)j * D_INNER + c * 512 + lane * 8];
            f32x4 w0 = wp[0], w1 = wp[1];
            #pragma unroll
            for (int u = 0; u < 4; ++u) acc += xf[c * 8 + u]     * w0[u];
            #pragma unroll
            for (int u = 0; u < 4; ++u) acc += xf[c * 8 + 4 + u] * w1[u];
        }
        acc += __shfl_xor(acc, 32); acc += __shfl_xor(acc, 16);
        acc += __shfl_xor(acc, 8);  acc += __shfl_xor(acc, 4);
        acc += __shfl_xor(acc, 2);  acc += __shfl_xor(acc, 1);
        if (lane == 0) xp_T[(size_t)j * NROW + row] = acc;
    }
}

// ---------------------------------------------------------------------------
// Transpose xc[row, d] -> xc_T[b*D_INNER+d, t] (unchanged from round 5).
// ---------------------------------------------------------------------------
__global__ __launch_bounds__(256) void transpose_k(const ushort_t* __restrict__ xc,
                                                   ushort_t* __restrict__ xc_T) {
    __shared__ ushort_t tileT[64][65];
    const int tid = threadIdx.x;
    const int t0 = blockIdx.x * 64, d0 = blockIdx.y * 64, b = blockIdx.z;
    const int dl = (tid & 7) * 8;
    const int tl = tid >> 3;
    #pragma unroll
    for (int it = 0; it < 2; ++it) {
        const int tt = tl + it * 32;
        short8 v = *(const short8*)&xc[(size_t)(b * SEQLEN + t0 + tt) * D_INNER + d0 + dl];
        #pragma unroll
        for (int k = 0; k < 8; ++k) tileT[dl + k][tt] = (ushort_t)v[k];
    }
    __syncthreads();
    const int tl2 = (tid & 7) * 8;
    const int dl2 = tid >> 3;
    #pragma unroll
    for (int it = 0; it < 2; ++it) {
        const int dd = dl2 + it * 32;
        short8 w = *(const short8*)&tileT[dd][tl2];
        *(short8*)&xc_T[(size_t)(b * D_INNER + d0 + dd) * SEQLEN + t0 + tl2] = w;
    }
}

#define BCAST_ALL(dst, src) \
    dst[0]=bcast16<0>(src);  dst[1]=bcast16<1>(src);  dst[2]=bcast16<2>(src);  dst[3]=bcast16<3>(src); \
    dst[4]=bcast16<4>(src);  dst[5]=bcast16<5>(src);  dst[6]=bcast16<6>(src);  dst[7]=bcast16<7>(src); \
    dst[8]=bcast16<8>(src);  dst[9]=bcast16<9>(src);  dst[10]=bcast16<10>(src); dst[11]=bcast16<11>(src); \
    dst[12]=bcast16<12>(src); dst[13]=bcast16<13>(src); dst[14]=bcast16<14>(src); dst[15]=bcast16<15>(src);

// ---------------------------------------------------------------------------
// Chunk-parallel selective scan, time-major reads, cooperative softplus.
// Lane = (channel, state): 4 channels x 16 states per wave.  Per 16-step
// block: lane s computes delta(t=T+s) once (identical fp32 formula), 16
// static ds_swizzle broadcasts distribute it; recurrence identical to the
// round-2..4 passing kernels.
// ---------------------------------------------------------------------------
__global__ __launch_bounds__(256) void scan_p1(const ushort_t* __restrict__ xc_T,
                                               const float* __restrict__ xp_T,
                                               const float* __restrict__ dt_w,
                                               const float* __restrict__ dt_b,
                                               const float* __restrict__ A_log,
                                               float* __restrict__ Pbuf,
                                               float* __restrict__ qbuf) {
    const int tid = threadIdx.x;
    const int s   = tid & 15;
    const int ch  = blockIdx.x * 16 + (tid >> 4);
    const int c   = blockIdx.y;
    const int b   = ch >> 11;
    const int d   = ch & (D_INNER - 1);
    const float A_s = -__expf(A_log[s]);
    const float dtw = dt_w[d];
    const float dtb = dt_b[d];
    const int rowbase = b * SEQLEN + c * CHUNKT;
    const ushort_t* xcp = xc_T + (size_t)ch * SEQLEN + c * CHUNKT;
    const float*    p0p = xp_T + rowbase;
    const float*    Bp  = xp_T + (size_t)(1 + s) * NROW + rowbase;
    float Acum = 1.f, wc = 0.f, prevA = 1.f;
    for (int T = 0; T < CHUNKT; T += 16) {
        const float dv_s = softplus_f(fmaf(p0p[s], dtw, dtb));   // 1 softplus / 16 steps
        float dvb[16];
        BCAST_ALL(dvb, dv_s)
        float Bf[16];
        #pragma unroll
        for (int q = 0; q < 4; ++q) ((f32x4*)Bf)[q] = ((const f32x4*)Bp)[q];
        const short8 xv0 = ((const short8*)xcp)[0];
        const short8 xv1 = ((const short8*)xcp)[1];
        #pragma unroll
        for (int k = 0; k < 16; ++k) {
            const float dv  = dvb[k];
            const float xcv = bf2f((ushort_t)(k < 8 ? xv0[k] : xv1[k - 8]));
            const float Ab  = fmaxf(__expf(dv * A_s), EPSF);
            prevA = Acum;
            Acum  = prevA * Ab;
            wc    = fmaf(dv * Bf[k] * xcv, frcp(fmaxf(prevA, EPSF)), wc);
        }
        xcp += 16; p0p += 16; Bp += 16;
    }
    const size_t base = ((size_t)c * NCH + ch) * 16 + s;
    Pbuf[base] = Acum;
    qbuf[base] = prevA * wc;
}

__global__ __launch_bounds__(256) void combine_k(const float* __restrict__ Pbuf,
                                                 const float* __restrict__ qbuf,
                                                 float* __restrict__ hbuf) {
    const int i = blockIdx.x * 256 + threadIdx.x;
    float h = 0.f;
    #pragma unroll
    for (int c = 0; c < NCHUNK; ++c) {
        const size_t idx = (size_t)c * (NCH * 16) + i;
        hbuf[idx] = h;                               // state ENTERING chunk c
        h = fmaf(Pbuf[idx], h, qbuf[idx]);
    }
}

__global__ __launch_bounds__(256) void scan_p2(const ushort_t* __restrict__ xc_T,
                                               const float* __restrict__ xp_T,
                                               const ushort_t* __restrict__ xz,
                                               const float* __restrict__ dt_w,
                                               const float* __restrict__ dt_b,
                                               const float* __restrict__ A_log,
                                               const float* __restrict__ D_par,
                                               const float* __restrict__ hbuf,
                                               ushort_t* __restrict__ G) {
    const int tid = threadIdx.x;
    const int s   = tid & 15;
    const int ch  = blockIdx.x * 16 + (tid >> 4);
    const int c   = blockIdx.y;
    const int b   = ch >> 11;
    const int d   = ch & (D_INNER - 1);
    const float A_s = -__expf(A_log[s]);
    const float dtw = dt_w[d];
    const float dtb = dt_b[d];
    const float Dp  = D_par[d];
    const float h0  = hbuf[((size_t)c * NCH + ch) * 16 + s];
    const int rowbase = b * SEQLEN + c * CHUNKT;
    const ushort_t* xcp  = xc_T + (size_t)ch * SEQLEN + c * CHUNKT;
    const float*    p0p  = xp_T + rowbase;
    const float*    Bp   = xp_T + (size_t)(1 + s) * NROW + rowbase;
    const float*    Cp   = xp_T + (size_t)(17 + s) * NROW + rowbase;
    const ushort_t* zcol = xz + (size_t)rowbase * (2 * D_INNER) + D_INNER + d;
    ushort_t*       Gcol = G  + (size_t)rowbase * D_INNER + d;
    float Acum = 1.f, wc = 0.f;
    for (int T = 0; T < CHUNKT; T += 16) {
        const float dv_s = softplus_f(fmaf(p0p[s], dtw, dtb));
        float dvb[16];
        BCAST_ALL(dvb, dv_s)
        float Bf[16], Cf[16];
        #pragma unroll
        for (int q = 0; q < 4; ++q) {
            ((f32x4*)Bf)[q] = ((const f32x4*)Bp)[q];
            ((f32x4*)Cf)[q] = ((const f32x4*)Cp)[q];
        }
        const short8 xv0 = ((const short8*)xcp)[0];
        const short8 xv1 = ((const short8*)xcp)[1];
        float myys = 0.f, myxcv = 0.f;
        #pragma unroll
        for (int k = 0; k < 16; ++k) {
            const float dv  = dvb[k];
            const float xcv = bf2f((ushort_t)(k < 8 ? xv0[k] : xv1[k - 8]));
            const float Ab  = fmaxf(__expf(dv * A_s), EPSF);
            const float prevA = Acum;
            Acum = prevA * Ab;
            wc   = fmaf(dv * Bf[k] * xcv, frcp(fmaxf(prevA, EPSF)), wc);
            const float h  = fmaf(prevA, wc, h0 * Acum);
            const float ys = sum16(Cf[k] * h);       // all 16 lanes get the sum
            if (s == k) { myys = ys; myxcv = xcv; }  // lane s owns t=T+s
        }
        // un-masked epilogue: each lane handles its own timestep t=T+s
        const float z = bf2f(zcol[(size_t)(T + s) * (2 * D_INNER)]);
        const float y = fmaf(Dp, myxcv, myys);
        Gcol[(size_t)(T + s) * D_INNER] = f2bf(y * z * frcp(1.f + __expf(-z)));
        xcp += 16; p0p += 16; Bp += 16; Cp += 16;
    }
}

// ---------------------------------------------------------------------------
extern "C" void kernel_launch(void* const* d_in, const int* in_sizes, int n_in,
                              void* d_out, int out_size, void* d_ws, size_t ws_size,
                              hipStream_t stream) {
    const float* x     = (const float*)d_in[0];
    const float* w_in  = (const float*)d_in[1];
    const float* cw    = (const float*)d_in[2];
    const float* cb    = (const float*)d_in[3];
    const float* w_xp  = (const float*)d_in[4];
    const float* dtw   = (const float*)d_in[5];
    const float* dtb   = (const float*)d_in[6];
    const float* alog  = (const float*)d_in[7];
    const float* dpar  = (const float*)d_in[8];
    const float* w_out = (const float*)d_in[9];
    float* out = (float*)d_out;

    char* ws = (char*)d_ws;
    const size_t MB = 1024ull * 1024ull;
    ushort_t* xz   = (ushort_t*)ws;                  // 32 MiB (xi|z), alive throughout
    ushort_t* xc   = (ushort_t*)(ws + 32 * MB);      // 16 MiB row-major; G overlays later
    float*    xp_T = (float*)   (ws + 48 * MB);      // 0.54 MiB [33, NROW]
    float*    Pbuf = (float*)   (ws + 49 * MB);      // 2 MiB
    float*    qbuf = (float*)   (ws + 51 * MB);      // 2 MiB
    float*    hbuf = (float*)   (ws + 53 * MB);      // 2 MiB
    ushort_t* xcT  = (ushort_t*)(ws + 55 * MB);      // 16 MiB [NCH, SEQLEN]  (total 71 MiB)
    ushort_t* G    = xc;                             // in-place over xc (dead after xproj+transpose)

    // 1) xz = x @ in_proj_w^T   (M=4096, N=4096, K=1024)
    hipLaunchKernelGGL((gemm_bt<D_MODEL, float, float, ushort_t>),
                       dim3(2 * D_INNER / 128, NROW / 128), dim3(256), 0, stream,
                       x, w_in, xz, 2 * D_INNER);
    // 2) xc = silu(causal depthwise conv(xi) + cb)
    hipLaunchKernelGGL(conv_silu_k, dim3(NROW * (D_INNER / 4) / 256), dim3(256), 0, stream,
                       xz, cw, cb, xc);
    // 3) xp_T = (xc @ x_proj_w^T)^T
    hipLaunchKernelGGL(xproj_k, dim3(NROW / 4), dim3(256), 0, stream, xc, w_xp, xp_T);
    // 3b) xc -> xc_T (time-major for the scan)
    hipLaunchKernelGGL(transpose_k, dim3(SEQLEN / 64, D_INNER / 64, BATCH), dim3(256), 0, stream,
                       xc, xcT);
    // 4a) per-chunk (P,q)
    hipLaunchKernelGGL(scan_p1, dim3(NCH / 16, NCHUNK), dim3(256), 0, stream,
                       xcT, xp_T, dtw, dtb, alog, Pbuf, qbuf);
    // 4b) chunk chain -> h0 per chunk
    hipLaunchKernelGGL(combine_k, dim3(NCH * 16 / 256), dim3(256), 0, stream,
                       Pbuf, qbuf, hbuf);
    // 4c) replay with h0, emit G = (C.h + D*x)*silu(z)  (in place over xc)
    hipLaunchKernelGGL(scan_p2, dim3(NCH / 16, NCHUNK), dim3(256), 0, stream,
                       xcT, xp_T, xz, dtw, dtb, alog, dpar, hbuf, G);
    // 5) out = G @ out_proj_w^T  (M=4096, N=1024, K=2048)
    hipLaunchKernelGGL((gemm_bt<D_INNER, ushort_t, float, float>),
                       dim3(D_MODEL / 128, NROW / 128), dim3(256), 0, stream,
                       G, w_out, out, D_MODEL);
    (void)in_sizes; (void)n_in; (void)out_size; (void)ws_size;
}

// Round 7
// 536.014 us; speedup vs baseline: 1.2251x; 1.0936x over previous
//
#include <hip/hip_runtime.h>
#include <hip/hip_bf16.h>
#include <math.h>

#define BATCH   2
#define SEQLEN  2048
#define D_MODEL 1024
#define D_INNER 2048
#define D_STATE 16
#define NCHUNK  8
#define CHUNKT  256
#define NROW    (BATCH * SEQLEN)   // 4096
#define NCH     (BATCH * D_INNER)  // 4096 channels
#define EPSF    1e-10f

typedef unsigned short ushort_t;
typedef __attribute__((ext_vector_type(8))) short short8;
typedef __attribute__((ext_vector_type(4))) float f32x4;

__device__ __forceinline__ float bf2f(ushort_t u) {
    union { unsigned int i; float f; } v; v.i = ((unsigned int)u) << 16; return v.f;
}
__device__ __forceinline__ ushort_t f2bf(float f) {
    union { float f; unsigned int i; } v; v.f = f;
    unsigned int r = v.i + 0x7FFFu + ((v.i >> 16) & 1u);   // RNE
    return (ushort_t)(r >> 16);
}
__device__ __forceinline__ float frcp(float x) {
#if __has_builtin(__builtin_amdgcn_rcpf)
    return __builtin_amdgcn_rcpf(x);
#else
    return 1.0f / x;
#endif
}
__device__ __forceinline__ float softplus_f(float u) {
    return fmaxf(u, 0.f) + __logf(1.f + __expf(-fabsf(u)));
}

// ds_swizzle broadcast: every lane in its 16-group receives lane K's value.
template<int K16>
__device__ __forceinline__ float bcast16(float x) {
    union { float f; int i; } a, b; a.f = x;
    b.i = __builtin_amdgcn_ds_swizzle(a.i, (K16 << 5) | 0x10);
    return b.f;
}
#define BCAST_ALL(dst, src) \
    dst[0]=bcast16<0>(src);  dst[1]=bcast16<1>(src);  dst[2]=bcast16<2>(src);  dst[3]=bcast16<3>(src); \
    dst[4]=bcast16<4>(src);  dst[5]=bcast16<5>(src);  dst[6]=bcast16<6>(src);  dst[7]=bcast16<7>(src); \
    dst[8]=bcast16<8>(src);  dst[9]=bcast16<9>(src);  dst[10]=bcast16<10>(src); dst[11]=bcast16<11>(src); \
    dst[12]=bcast16<12>(src); dst[13]=bcast16<13>(src); dst[14]=bcast16<14>(src); dst[15]=bcast16<15>(src);

// 8 contiguous fp32 -> bf16 short8
__device__ __forceinline__ short8 ld8bf(const float* p) {
    f32x4 a = ((const f32x4*)p)[0];
    f32x4 b = ((const f32x4*)p)[1];
    short8 r;
    r[0] = (short)f2bf(a[0]); r[1] = (short)f2bf(a[1]);
    r[2] = (short)f2bf(a[2]); r[3] = (short)f2bf(a[3]);
    r[4] = (short)f2bf(b[0]); r[5] = (short)f2bf(b[1]);
    r[6] = (short)f2bf(b[2]); r[7] = (short)f2bf(b[3]);
    return r;
}
__device__ __forceinline__ void st1(float* p, float v)    { *p = v; }
__device__ __forceinline__ void st1(ushort_t* p, float v) { *p = f2bf(v); }

// async global(16B/lane) -> LDS (wave-uniform base + lane*16)
__device__ __forceinline__ void async_ld16(const ushort_t* g, ushort_t* l) {
    __builtin_amdgcn_global_load_lds(
        (const __attribute__((address_space(1))) unsigned int*)g,
        (__attribute__((address_space(3))) unsigned int*)l, 16, 0, 0);
}

// ---------------------------------------------------------------------------
// fp32 -> bf16 convert (for GEMM operands)
// ---------------------------------------------------------------------------
__global__ __launch_bounds__(256) void cvt_bf16_k(const float* __restrict__ in,
                                                  ushort_t* __restrict__ out) {
    const int i = (blockIdx.x * 256 + threadIdx.x) * 8;
    *(short8*)&out[i] = ld8bf(&in[i]);
}

// ---------------------------------------------------------------------------
// m97-style GEMM: C[M,N] = A[M,K] @ B[N,K]^T, A/B bf16 (pre-converted),
// global_load_lds width-16 staging into UNPADDED [128][32] LDS tiles
// (lane*16B == row-major offset: (i>>2)*32 + (i&3)*8 shorts == i*8).
// 128x128 tile, 4 waves 2x2, 4x4 mfma_f32_16x16x32_bf16 per wave.
// ---------------------------------------------------------------------------
template<int K, typename TC>
__global__ __launch_bounds__(256) void gemm_lds(const ushort_t* __restrict__ A,
                                                const ushort_t* __restrict__ B,
                                                TC* __restrict__ C, int N) {
    __shared__ alignas(16) ushort_t As[128 * 32];
    __shared__ alignas(16) ushort_t Bs[128 * 32];
    const int tid  = threadIdx.x;
    const int wave = tid >> 6, lane = tid & 63;
    const int wm = (wave >> 1) * 64, wn = (wave & 1) * 64;
    const int row0 = blockIdx.y * 128, col0 = blockIdx.x * 128;
    f32x4 acc[4][4] = {};
    // staging: wave w covers tile rows [w*32, w*32+32), two instrs of 16 rows
    const int srow = wave * 32 + (lane >> 2);
    const int scol = (lane & 3) * 8;                    // shorts
    const ushort_t* Ag = A + (size_t)(row0 + srow) * K + scol;
    const ushort_t* Bg = B + (size_t)(col0 + srow) * K + scol;
    ushort_t* Al = As + (wave * 32) * 32;               // wave-uniform LDS base
    ushort_t* Bl = Bs + (wave * 32) * 32;
    const int fr = lane & 15;
    const int fk = (lane >> 4) * 8;                     // shorts
    for (int k0 = 0; k0 < K; k0 += 32) {
        async_ld16(Ag,            Al);
        async_ld16(Ag + 16 * K,   Al + 16 * 32);
        async_ld16(Bg,            Bl);
        async_ld16(Bg + 16 * K,   Bl + 16 * 32);
        __syncthreads();                                // drains vmcnt
        short8 af[4], bfr[4];
        #pragma unroll
        for (int i = 0; i < 4; ++i) {
            af[i]  = *(const short8*)&As[(wm + i * 16 + fr) * 32 + fk];
            bfr[i] = *(const short8*)&Bs[(wn + i * 16 + fr) * 32 + fk];
        }
        #pragma unroll
        for (int i = 0; i < 4; ++i)
            #pragma unroll
            for (int j = 0; j < 4; ++j)
                acc[i][j] = __builtin_amdgcn_mfma_f32_16x16x32_bf16(af[i], bfr[j], acc[i][j], 0, 0, 0);
        __syncthreads();
        Ag += 32; Bg += 32;
    }
    const int quad = lane >> 4;
    #pragma unroll
    for (int i = 0; i < 4; ++i)
        #pragma unroll
        for (int j = 0; j < 4; ++j)
            #pragma unroll
            for (int r = 0; r < 4; ++r) {
                // m89-verified C/D layout: col = lane&15, row = (lane>>4)*4 + reg
                int row = row0 + wm + i * 16 + quad * 4 + r;
                int col = col0 + wn + j * 16 + fr;
                st1(&C[(size_t)row * N + col], acc[i][j][r]);
            }
}

// ---------------------------------------------------------------------------
// Depthwise causal conv (k=4) + bias + SiLU (unchanged).
// ---------------------------------------------------------------------------
__global__ __launch_bounds__(256) void conv_silu_k(const ushort_t* __restrict__ xz,
                                                   const float* __restrict__ cw,
                                                   const float* __restrict__ cb,
                                                   ushort_t* __restrict__ xc) {
    int idx = blockIdx.x * 256 + threadIdx.x;
    int d4  = (idx & (D_INNER / 4 - 1)) * 4;
    int row = idx >> 9;
    int t   = row & (SEQLEN - 1);
    float a[4] = {0.f, 0.f, 0.f, 0.f};
    #pragma unroll
    for (int j = 0; j < 4; ++j) {
        int tt = t - 3 + j;
        if (tt >= 0) {
            const ushort_t* p = &xz[(size_t)(row - 3 + j) * (2 * D_INNER) + d4];
            #pragma unroll
            for (int u = 0; u < 4; ++u)
                a[u] += cw[(d4 + u) * 4 + j] * bf2f(p[u]);
        }
    }
    #pragma unroll
    for (int u = 0; u < 4; ++u) {
        float v  = a[u] + cb[d4 + u];
        float sv = v / (1.f + expf(-v));
        xc[(size_t)row * D_INNER + d4 + u] = f2bf(sv);
    }
}

// ---------------------------------------------------------------------------
// x_proj: xp_T[j, row] (transposed store; unchanged).
// ---------------------------------------------------------------------------
__global__ __launch_bounds__(256) void xproj_k(const ushort_t* __restrict__ xc,
                                               const float* __restrict__ w,
                                               float* __restrict__ xp_T) {
    int row  = blockIdx.x * 4 + (threadIdx.x >> 6);
    int lane = threadIdx.x & 63;
    const ushort_t* xr = xc + (size_t)row * D_INNER;
    float xf[32];
    #pragma unroll
    for (int c = 0; c < 4; ++c) {
        short8 xv = *(const short8*)&xr[c * 512 + lane * 8];
        #pragma unroll
        for (int u = 0; u < 8; ++u) xf[c * 8 + u] = bf2f((ushort_t)xv[u]);
    }
    for (int j = 0; j < 33; ++j) {
        float acc = 0.f;
        #pragma unroll
        for (int c = 0; c < 4; ++c) {
            const f32x4* wp = (const f32x4*)&w[(size_t)j * D_INNER + c * 512 + lane * 8];
            f32x4 w0 = wp[0], w1 = wp[1];
            #pragma unroll
            for (int u = 0; u < 4; ++u) acc += xf[c * 8 + u]     * w0[u];
            #pragma unroll
            for (int u = 0; u < 4; ++u) acc += xf[c * 8 + 4 + u] * w1[u];
        }
        acc += __shfl_xor(acc, 32); acc += __shfl_xor(acc, 16);
        acc += __shfl_xor(acc, 8);  acc += __shfl_xor(acc, 4);
        acc += __shfl_xor(acc, 2);  acc += __shfl_xor(acc, 1);
        if (lane == 0) xp_T[(size_t)j * NROW + row] = acc;
    }
}

// ---------------------------------------------------------------------------
// Transpose xc[row, d] -> xc_T[b*D_INNER+d, t] (unchanged).
// ---------------------------------------------------------------------------
__global__ __launch_bounds__(256) void transpose_k(const ushort_t* __restrict__ xc,
                                                   ushort_t* __restrict__ xc_T) {
    __shared__ ushort_t tileT[64][65];
    const int tid = threadIdx.x;
    const int t0 = blockIdx.x * 64, d0 = blockIdx.y * 64, b = blockIdx.z;
    const int dl = (tid & 7) * 8;
    const int tl = tid >> 3;
    #pragma unroll
    for (int it = 0; it < 2; ++it) {
        const int tt = tl + it * 32;
        short8 v = *(const short8*)&xc[(size_t)(b * SEQLEN + t0 + tt) * D_INNER + d0 + dl];
        #pragma unroll
        for (int k = 0; k < 8; ++k) tileT[dl + k][tt] = (ushort_t)v[k];
    }
    __syncthreads();
    const int tl2 = (tid & 7) * 8;
    const int dl2 = tid >> 3;
    #pragma unroll
    for (int it = 0; it < 2; ++it) {
        const int dd = dl2 + it * 32;
        short8 w = *(const short8*)&tileT[dd][tl2];
        *(short8*)&xc_T[(size_t)(b * D_INNER + d0 + dd) * SEQLEN + t0 + tl2] = w;
    }
}

// ---------------------------------------------------------------------------
// Chunk-parallel selective scan (pass 1: per-chunk (P,q); unchanged).
// ---------------------------------------------------------------------------
__global__ __launch_bounds__(256) void scan_p1(const ushort_t* __restrict__ xc_T,
                                               const float* __restrict__ xp_T,
                                               const float* __restrict__ dt_w,
                                               const float* __restrict__ dt_b,
                                               const float* __restrict__ A_log,
                                               float* __restrict__ Pbuf,
                                               float* __restrict__ qbuf) {
    const int tid = threadIdx.x;
    const int s   = tid & 15;
    const int ch  = blockIdx.x * 16 + (tid >> 4);
    const int c   = blockIdx.y;
    const int b   = ch >> 11;
    const int d   = ch & (D_INNER - 1);
    const float A_s = -__expf(A_log[s]);
    const float dtw = dt_w[d];
    const float dtb = dt_b[d];
    const int rowbase = b * SEQLEN + c * CHUNKT;
    const ushort_t* xcp = xc_T + (size_t)ch * SEQLEN + c * CHUNKT;
    const float*    p0p = xp_T + rowbase;
    const float*    Bp  = xp_T + (size_t)(1 + s) * NROW + rowbase;
    float Acum = 1.f, wc = 0.f, prevA = 1.f;
    for (int T = 0; T < CHUNKT; T += 16) {
        const float dv_s = softplus_f(fmaf(p0p[s], dtw, dtb));   // 1 softplus / 16 steps
        float dvb[16];
        BCAST_ALL(dvb, dv_s)
        float Bf[16];
        #pragma unroll
        for (int q = 0; q < 4; ++q) ((f32x4*)Bf)[q] = ((const f32x4*)Bp)[q];
        const short8 xv0 = ((const short8*)xcp)[0];
        const short8 xv1 = ((const short8*)xcp)[1];
        #pragma unroll
        for (int k = 0; k < 16; ++k) {
            const float dv  = dvb[k];
            const float xcv = bf2f((ushort_t)(k < 8 ? xv0[k] : xv1[k - 8]));
            const float Ab  = fmaxf(__expf(dv * A_s), EPSF);
            prevA = Acum;
            Acum  = prevA * Ab;
            wc    = fmaf(dv * Bf[k] * xcv, frcp(fmaxf(prevA, EPSF)), wc);
        }
        xcp += 16; p0p += 16; Bp += 16;
    }
    const size_t base = ((size_t)c * NCH + ch) * 16 + s;
    Pbuf[base] = Acum;
    qbuf[base] = prevA * wc;
}

__global__ __launch_bounds__(256) void combine_k(const float* __restrict__ Pbuf,
                                                 const float* __restrict__ qbuf,
                                                 float* __restrict__ hbuf) {
    const int i = blockIdx.x * 256 + threadIdx.x;
    float h = 0.f;
    #pragma unroll
    for (int c = 0; c < NCHUNK; ++c) {
        const size_t idx = (size_t)c * (NCH * 16) + i;
        hbuf[idx] = h;                               // state ENTERING chunk c
        h = fmaf(Pbuf[idx], h, qbuf[idx]);
    }
}

// ---------------------------------------------------------------------------
// Pass 2: replay + output.  Reduction via wave-private LDS transpose:
// step k writes red[gi][k][s] = C*h + (s==0)*Dp*xcv (one independent
// ds_write_b32); per 16 steps lane s sums its row (4 independent
// ds_read_b128, linear s-order).  No dependent DS chains, no exec masking.
// Row stride 20 floats keeps 16B alignment; group stride 324 floats breaks
// the 16-group bank collision (gi*324 mod 32 banks = 4*gi).
// ---------------------------------------------------------------------------
__global__ __launch_bounds__(256) void scan_p2(const ushort_t* __restrict__ xc_T,
                                               const float* __restrict__ xp_T,
                                               const ushort_t* __restrict__ xz,
                                               const float* __restrict__ dt_w,
                                               const float* __restrict__ dt_b,
                                               const float* __restrict__ A_log,
                                               const float* __restrict__ D_par,
                                               const float* __restrict__ hbuf,
                                               ushort_t* __restrict__ G) {
    __shared__ alignas(16) float red[16 * 324];
    const int tid = threadIdx.x;
    const int s   = tid & 15;
    const int gi  = tid >> 4;
    const int ch  = blockIdx.x * 16 + gi;
    const int c   = blockIdx.y;
    const int b   = ch >> 11;
    const int d   = ch & (D_INNER - 1);
    const float A_s   = -__expf(A_log[s]);
    const float dtw   = dt_w[d];
    const float dtb   = dt_b[d];
    const float dterm = (s == 0) ? D_par[d] : 0.f;   // folds D*x into the s-sum
    const float h0    = hbuf[((size_t)c * NCH + ch) * 16 + s];
    const int rowbase = b * SEQLEN + c * CHUNKT;
    const ushort_t* xcp  = xc_T + (size_t)ch * SEQLEN + c * CHUNKT;
    const float*    p0p  = xp_T + rowbase;
    const float*    Bp   = xp_T + (size_t)(1 + s) * NROW + rowbase;
    const float*    Cp   = xp_T + (size_t)(17 + s) * NROW + rowbase;
    const ushort_t* zcol = xz + (size_t)rowbase * (2 * D_INNER) + D_INNER + d;
    ushort_t*       Gcol = G  + (size_t)rowbase * D_INNER + d;
    float* redw = &red[gi * 324];
    float Acum = 1.f, wc = 0.f;
    for (int T = 0; T < CHUNKT; T += 16) {
        const float dv_s = softplus_f(fmaf(p0p[s], dtw, dtb));
        float dvb[16];
        BCAST_ALL(dvb, dv_s)
        float Bf[16], Cf[16];
        #pragma unroll
        for (int q = 0; q < 4; ++q) {
            ((f32x4*)Bf)[q] = ((const f32x4*)Bp)[q];
            ((f32x4*)Cf)[q] = ((const f32x4*)Cp)[q];
        }
        const short8 xv0 = ((const short8*)xcp)[0];
        const short8 xv1 = ((const short8*)xcp)[1];
        #pragma unroll
        for (int k = 0; k < 16; ++k) {
            const float dv  = dvb[k];
            const float xcv = bf2f((ushort_t)(k < 8 ? xv0[k] : xv1[k - 8]));
            const float Ab  = fmaxf(__expf(dv * A_s), EPSF);
            const float prevA = Acum;
            Acum = prevA * Ab;
            wc   = fmaf(dv * Bf[k] * xcv, frcp(fmaxf(prevA, EPSF)), wc);
            const float h = fmaf(prevA, wc, h0 * Acum);
            redw[k * 20 + s] = fmaf(dterm, xcv, Cf[k] * h);
        }
        // lane s sums row s (timestep t = T+s) over the 16 states
        const float* rrow = &redw[s * 20];
        float y = 0.f;
        #pragma unroll
        for (int q = 0; q < 4; ++q) {
            const f32x4 r = ((const f32x4*)rrow)[q];
            y += r[0]; y += r[1]; y += r[2]; y += r[3];
        }
        const float z = bf2f(zcol[(size_t)(T + s) * (2 * D_INNER)]);
        Gcol[(size_t)(T + s) * D_INNER] = f2bf(y * z * frcp(1.f + __expf(-z)));
        xcp += 16; p0p += 16; Bp += 16; Cp += 16;
    }
}

// ---------------------------------------------------------------------------
extern "C" void kernel_launch(void* const* d_in, const int* in_sizes, int n_in,
                              void* d_out, int out_size, void* d_ws, size_t ws_size,
                              hipStream_t stream) {
    const float* x     = (const float*)d_in[0];
    const float* w_in  = (const float*)d_in[1];
    const float* cw    = (const float*)d_in[2];
    const float* cb    = (const float*)d_in[3];
    const float* w_xp  = (const float*)d_in[4];
    const float* dtw   = (const float*)d_in[5];
    const float* dtb   = (const float*)d_in[6];
    const float* alog  = (const float*)d_in[7];
    const float* dpar  = (const float*)d_in[8];
    const float* w_out = (const float*)d_in[9];
    float* out = (float*)d_out;

    char* ws = (char*)d_ws;
    const size_t MB = 1024ull * 1024ull;
    // Persistent regions:
    ushort_t* xz   = (ushort_t*)ws;                  // 0-32 MiB (xi|z)
    ushort_t* xc   = (ushort_t*)(ws + 32 * MB);      // 32-48 MiB; G overlays later
    float*    xp_T = (float*)   (ws + 48 * MB);      // 48-48.6 MiB [33, NROW]
    float*    Pbuf = (float*)   (ws + 49 * MB);      // 49-51 MiB
    float*    qbuf = (float*)   (ws + 51 * MB);      // 51-53 MiB
    float*    hbuf = (float*)   (ws + 53 * MB);      // 53-55 MiB
    ushort_t* xcT  = (ushort_t*)(ws + 55 * MB);      // 55-71 MiB [NCH, SEQLEN]
    // Temporally-overlaid bf16 GEMM operands (dead before their regions' users):
    ushort_t* xb   = (ushort_t*)(ws + 48 * MB);      // 48-56 MiB, dead after gemm1
    ushort_t* winb = (ushort_t*)(ws + 56 * MB);      // 56-64 MiB, dead after gemm1
    ushort_t* wob  = (ushort_t*)(ws + 49 * MB);      // 49-53 MiB, written after combine
    ushort_t* G    = xc;                             // in-place over xc

    // 0) bf16 conversions for gemm1
    hipLaunchKernelGGL(cvt_bf16_k, dim3(NROW * D_MODEL / 2048), dim3(256), 0, stream, x, xb);
    hipLaunchKernelGGL(cvt_bf16_k, dim3(2 * D_INNER * D_MODEL / 2048), dim3(256), 0, stream, w_in, winb);
    // 1) xz = x @ in_proj_w^T   (M=4096, N=4096, K=1024)
    hipLaunchKernelGGL((gemm_lds<D_MODEL, ushort_t>),
                       dim3(2 * D_INNER / 128, NROW / 128), dim3(256), 0, stream,
                       xb, winb, xz, 2 * D_INNER);
    // 2) xc = silu(causal depthwise conv(xi) + cb)
    hipLaunchKernelGGL(conv_silu_k, dim3(NROW * (D_INNER / 4) / 256), dim3(256), 0, stream,
                       xz, cw, cb, xc);
    // 3) xp_T = (xc @ x_proj_w^T)^T
    hipLaunchKernelGGL(xproj_k, dim3(NROW / 4), dim3(256), 0, stream, xc, w_xp, xp_T);
    // 3b) xc -> xc_T (time-major for the scan)
    hipLaunchKernelGGL(transpose_k, dim3(SEQLEN / 64, D_INNER / 64, BATCH), dim3(256), 0, stream,
                       xc, xcT);
    // 4a) per-chunk (P,q)
    hipLaunchKernelGGL(scan_p1, dim3(NCH / 16, NCHUNK), dim3(256), 0, stream,
                       xcT, xp_T, dtw, dtb, alog, Pbuf, qbuf);
    // 4b) chunk chain -> h0 per chunk
    hipLaunchKernelGGL(combine_k, dim3(NCH * 16 / 256), dim3(256), 0, stream,
                       Pbuf, qbuf, hbuf);
    // 4c) convert w_out (into dead Pbuf/qbuf region)
    hipLaunchKernelGGL(cvt_bf16_k, dim3(D_MODEL * D_INNER / 2048), dim3(256), 0, stream, w_out, wob);
    // 4d) replay with h0, emit G = (C.h + D*x)*silu(z)  (in place over xc)
    hipLaunchKernelGGL(scan_p2, dim3(NCH / 16, NCHUNK), dim3(256), 0, stream,
                       xcT, xp_T, xz, dtw, dtb, alog, dpar, hbuf, G);
    // 5) out = G @ out_proj_w^T  (M=4096, N=1024, K=2048)
    hipLaunchKernelGGL((gemm_lds<D_INNER, float>),
                       dim3(D_MODEL / 128, NROW / 128), dim3(256), 0, stream,
                       G, wob, out, D_MODEL);
    (void)in_sizes; (void)n_in; (void)out_size; (void)ws_size;
}

// Round 8
// 479.074 us; speedup vs baseline: 1.3707x; 1.1189x over previous
//
#include <hip/hip_runtime.h>
#include <hip/hip_bf16.h>
#include <math.h>

#define BATCH   2
#define SEQLEN  2048
#define D_MODEL 1024
#define D_INNER 2048
#define D_STATE 16
#define NCHUNK  8
#define CHUNKT  256
#define NROW    (BATCH * SEQLEN)   // 4096
#define NCH     (BATCH * D_INNER)  // 4096 channels
#define EPSF    1e-10f

typedef unsigned short ushort_t;
typedef __attribute__((ext_vector_type(8))) short short8;
typedef __attribute__((ext_vector_type(4))) float f32x4;

__device__ __forceinline__ float bf2f(ushort_t u) {
    union { unsigned int i; float f; } v; v.i = ((unsigned int)u) << 16; return v.f;
}
__device__ __forceinline__ ushort_t f2bf(float f) {
    union { float f; unsigned int i; } v; v.f = f;
    unsigned int r = v.i + 0x7FFFu + ((v.i >> 16) & 1u);   // RNE
    return (ushort_t)(r >> 16);
}
__device__ __forceinline__ float frcp(float x) {
#if __has_builtin(__builtin_amdgcn_rcpf)
    return __builtin_amdgcn_rcpf(x);
#else
    return 1.0f / x;
#endif
}
__device__ __forceinline__ float softplus_f(float u) {
    return fmaxf(u, 0.f) + __logf(1.f + __expf(-fabsf(u)));
}

// ds_swizzle broadcast: every lane in its 16-group receives lane K's value.
template<int K16>
__device__ __forceinline__ float bcast16(float x) {
    union { float f; int i; } a, b; a.f = x;
    b.i = __builtin_amdgcn_ds_swizzle(a.i, (K16 << 5) | 0x10);
    return b.f;
}
#define BCAST_ALL(dst, src) \
    dst[0]=bcast16<0>(src);  dst[1]=bcast16<1>(src);  dst[2]=bcast16<2>(src);  dst[3]=bcast16<3>(src); \
    dst[4]=bcast16<4>(src);  dst[5]=bcast16<5>(src);  dst[6]=bcast16<6>(src);  dst[7]=bcast16<7>(src); \
    dst[8]=bcast16<8>(src);  dst[9]=bcast16<9>(src);  dst[10]=bcast16<10>(src); dst[11]=bcast16<11>(src); \
    dst[12]=bcast16<12>(src); dst[13]=bcast16<13>(src); dst[14]=bcast16<14>(src); dst[15]=bcast16<15>(src);

// value from lane (s^8) within the 16-group
__device__ __forceinline__ float swz_xor8(float x) {
    union { float f; int i; } a, b; a.f = x;
    b.i = __builtin_amdgcn_ds_swizzle(a.i, (8 << 10) | 0x1F);
    return b.f;
}

// 8 contiguous fp32 -> bf16 short8
__device__ __forceinline__ short8 ld8bf(const float* p) {
    f32x4 a = ((const f32x4*)p)[0];
    f32x4 b = ((const f32x4*)p)[1];
    short8 r;
    r[0] = (short)f2bf(a[0]); r[1] = (short)f2bf(a[1]);
    r[2] = (short)f2bf(a[2]); r[3] = (short)f2bf(a[3]);
    r[4] = (short)f2bf(b[0]); r[5] = (short)f2bf(b[1]);
    r[6] = (short)f2bf(b[2]); r[7] = (short)f2bf(b[3]);
    return r;
}
__device__ __forceinline__ void st1(float* p, float v)    { *p = v; }
__device__ __forceinline__ void st1(ushort_t* p, float v) { *p = f2bf(v); }

// async global(16B/lane) -> LDS (wave-uniform base + lane*16)
__device__ __forceinline__ void async_ld16(const ushort_t* g, ushort_t* l) {
    __builtin_amdgcn_global_load_lds(
        (const __attribute__((address_space(1))) unsigned int*)g,
        (__attribute__((address_space(3))) unsigned int*)l, 16, 0, 0);
}

// ---------------------------------------------------------------------------
// fp32 -> bf16 convert (GEMM operands)
// ---------------------------------------------------------------------------
__global__ __launch_bounds__(256) void cvt_bf16_k(const float* __restrict__ in,
                                                  ushort_t* __restrict__ out) {
    const int i = (blockIdx.x * 256 + threadIdx.x) * 8;
    *(short8*)&out[i] = ld8bf(&in[i]);
}

// ---------------------------------------------------------------------------
// gemm1: xz = x @ in_proj_w^T, split epilogue:
//   cols <  D_INNER -> xi[row, col]              (bf16 row-major, for conv)
//   cols >= D_INNER -> gz_T[ch, t] = silu(acc)   (bf16 time-major, pre-gated)
// m97-style global_load_lds staging, 128x128 tile, 4 waves 2x2.
// ---------------------------------------------------------------------------
__global__ __launch_bounds__(256) void gemm1_k(const ushort_t* __restrict__ A,
                                               const ushort_t* __restrict__ B,
                                               ushort_t* __restrict__ xi,
                                               ushort_t* __restrict__ gzT) {
    constexpr int K = D_MODEL;
    __shared__ alignas(16) ushort_t As[128 * 32];
    __shared__ alignas(16) ushort_t Bs[128 * 32];
    const int tid  = threadIdx.x;
    const int wave = tid >> 6, lane = tid & 63;
    const int wm = (wave >> 1) * 64, wn = (wave & 1) * 64;
    const int row0 = blockIdx.y * 128, col0 = blockIdx.x * 128;
    f32x4 acc[4][4] = {};
    const int srow = wave * 32 + (lane >> 2);
    const int scol = (lane & 3) * 8;
    const ushort_t* Ag = A + (size_t)(row0 + srow) * K + scol;
    const ushort_t* Bg = B + (size_t)(col0 + srow) * K + scol;
    ushort_t* Al = As + (wave * 32) * 32;
    ushort_t* Bl = Bs + (wave * 32) * 32;
    const int fr = lane & 15;
    const int fk = (lane >> 4) * 8;
    for (int k0 = 0; k0 < K; k0 += 32) {
        async_ld16(Ag,          Al);
        async_ld16(Ag + 16 * K, Al + 16 * 32);
        async_ld16(Bg,          Bl);
        async_ld16(Bg + 16 * K, Bl + 16 * 32);
        __syncthreads();
        short8 af[4], bfr[4];
        #pragma unroll
        for (int i = 0; i < 4; ++i) {
            af[i]  = *(const short8*)&As[(wm + i * 16 + fr) * 32 + fk];
            bfr[i] = *(const short8*)&Bs[(wn + i * 16 + fr) * 32 + fk];
        }
        #pragma unroll
        for (int i = 0; i < 4; ++i)
            #pragma unroll
            for (int j = 0; j < 4; ++j)
                acc[i][j] = __builtin_amdgcn_mfma_f32_16x16x32_bf16(af[i], bfr[j], acc[i][j], 0, 0, 0);
        __syncthreads();
        Ag += 32; Bg += 32;
    }
    const int quad = lane >> 4;
    const bool zhalf = (col0 >= D_INNER);
    #pragma unroll
    for (int i = 0; i < 4; ++i)
        #pragma unroll
        for (int j = 0; j < 4; ++j)
            #pragma unroll
            for (int r = 0; r < 4; ++r) {
                const int row = row0 + wm + i * 16 + quad * 4 + r;
                const int col = col0 + wn + j * 16 + fr;
                const float v = acc[i][j][r];
                if (!zhalf) {
                    xi[(size_t)row * D_INNER + col] = f2bf(v);
                } else {
                    const float g = v * frcp(1.f + __expf(-v));   // silu in fp32
                    const int bb = row >> 11, t = row & (SEQLEN - 1);
                    const int dd = col - D_INNER;
                    gzT[((size_t)(bb * D_INNER + dd)) * SEQLEN + t] = f2bf(g);
                }
            }
}

// ---------------------------------------------------------------------------
// Fused depthwise causal conv (k=4) + bias + SiLU + transpose.
// Reads xi[row, d] (block working set ~8.5 KB -> L1); writes xc[row, d]
// (row-major, for xproj) AND xc_T[ch, t] (time-major via LDS tile, for scan).
// ---------------------------------------------------------------------------
__global__ __launch_bounds__(256) void conv_t_k(const ushort_t* __restrict__ xi,
                                                const float* __restrict__ cw,
                                                const float* __restrict__ cb,
                                                ushort_t* __restrict__ xc,
                                                ushort_t* __restrict__ xc_T) {
    __shared__ ushort_t tileT[64][65];
    const int tid = threadIdx.x;
    const int t0 = blockIdx.x * 64, d0 = blockIdx.y * 64, b = blockIdx.z;
    const int dl = (tid & 7) * 8;     // 8 channels
    const int tl = tid >> 3;          // 0..31
    float w[8][4], bias[8];
    #pragma unroll
    for (int u = 0; u < 8; ++u) {
        #pragma unroll
        for (int j = 0; j < 4; ++j) w[u][j] = cw[(d0 + dl + u) * 4 + j];
        bias[u] = cb[d0 + dl + u];
    }
    #pragma unroll
    for (int it = 0; it < 2; ++it) {
        const int t   = t0 + tl + it * 32;
        const int row = b * SEQLEN + t;
        float a[8];
        #pragma unroll
        for (int u = 0; u < 8; ++u) a[u] = bias[u];
        #pragma unroll
        for (int j = 0; j < 4; ++j) {
            const int tt = t - 3 + j;
            if (tt >= 0) {
                short8 v = *(const short8*)&xi[(size_t)(b * SEQLEN + tt) * D_INNER + d0 + dl];
                #pragma unroll
                for (int u = 0; u < 8; ++u) a[u] += w[u][j] * bf2f((ushort_t)v[u]);
            }
        }
        short8 o;
        #pragma unroll
        for (int u = 0; u < 8; ++u) {
            const float sv = a[u] / (1.f + expf(-a[u]));
            o[u] = (short)f2bf(sv);
        }
        *(short8*)&xc[(size_t)row * D_INNER + d0 + dl] = o;
        #pragma unroll
        for (int u = 0; u < 8; ++u) tileT[dl + u][tl + it * 32] = (ushort_t)o[u];
    }
    __syncthreads();
    const int tl2 = (tid & 7) * 8;
    const int dl2 = tid >> 3;
    #pragma unroll
    for (int it = 0; it < 2; ++it) {
        const int dd = dl2 + it * 32;
        short8 v = *(const short8*)&tileT[dd][tl2];
        *(short8*)&xc_T[(size_t)(b * D_INNER + d0 + dd) * SEQLEN + t0 + tl2] = v;
    }
}

// ---------------------------------------------------------------------------
// x_proj: xp_T[j, row] (transposed store; unchanged).
// ---------------------------------------------------------------------------
__global__ __launch_bounds__(256) void xproj_k(const ushort_t* __restrict__ xc,
                                               const float* __restrict__ w,
                                               float* __restrict__ xp_T) {
    int row  = blockIdx.x * 4 + (threadIdx.x >> 6);
    int lane = threadIdx.x & 63;
    const ushort_t* xr = xc + (size_t)row * D_INNER;
    float xf[32];
    #pragma unroll
    for (int c = 0; c < 4; ++c) {
        short8 xv = *(const short8*)&xr[c * 512 + lane * 8];
        #pragma unroll
        for (int u = 0; u < 8; ++u) xf[c * 8 + u] = bf2f((ushort_t)xv[u]);
    }
    for (int j = 0; j < 33; ++j) {
        float acc = 0.f;
        #pragma unroll
        for (int c = 0; c < 4; ++c) {
            const f32x4* wp = (const f32x4*)&w[(size_t)j * D_INNER + c * 512 + lane * 8];
            f32x4 w0 = wp[0], w1 = wp[1];
            #pragma unroll
            for (int u = 0; u < 4; ++u) acc += xf[c * 8 + u]     * w0[u];
            #pragma unroll
            for (int u = 0; u < 4; ++u) acc += xf[c * 8 + 4 + u] * w1[u];
        }
        acc += __shfl_xor(acc, 32); acc += __shfl_xor(acc, 16);
        acc += __shfl_xor(acc, 8);  acc += __shfl_xor(acc, 4);
        acc += __shfl_xor(acc, 2);  acc += __shfl_xor(acc, 1);
        if (lane == 0) xp_T[(size_t)j * NROW + row] = acc;
    }
}

// ---------------------------------------------------------------------------
// Scan pass 1: per-chunk (P,q).  Unchanged recurrence (round-7 validated).
// ---------------------------------------------------------------------------
__global__ __launch_bounds__(256) void scan_p1(const ushort_t* __restrict__ xc_T,
                                               const float* __restrict__ xp_T,
                                               const float* __restrict__ dt_w,
                                               const float* __restrict__ dt_b,
                                               const float* __restrict__ A_log,
                                               float* __restrict__ Pbuf,
                                               float* __restrict__ qbuf) {
    const int tid = threadIdx.x;
    const int s   = tid & 15;
    const int ch  = blockIdx.x * 16 + (tid >> 4);
    const int c   = blockIdx.y;
    const int b   = ch >> 11;
    const int d   = ch & (D_INNER - 1);
    const float A_s = -__expf(A_log[s]);
    const float dtw = dt_w[d];
    const float dtb = dt_b[d];
    const int rowbase = b * SEQLEN + c * CHUNKT;
    const ushort_t* xcp = xc_T + (size_t)ch * SEQLEN + c * CHUNKT;
    const float*    p0p = xp_T + rowbase;
    const float*    Bp  = xp_T + (size_t)(1 + s) * NROW + rowbase;
    float Acum = 1.f, wc = 0.f, prevA = 1.f;
    for (int T = 0; T < CHUNKT; T += 16) {
        const float dv_s = softplus_f(fmaf(p0p[s], dtw, dtb));   // 1 softplus / 16 steps
        float dvb[16];
        BCAST_ALL(dvb, dv_s)
        float Bf[16];
        #pragma unroll
        for (int q = 0; q < 4; ++q) ((f32x4*)Bf)[q] = ((const f32x4*)Bp)[q];
        const short8 xv0 = ((const short8*)xcp)[0];
        const short8 xv1 = ((const short8*)xcp)[1];
        #pragma unroll
        for (int k = 0; k < 16; ++k) {
            const float dv  = dvb[k];
            const float xcv = bf2f((ushort_t)(k < 8 ? xv0[k] : xv1[k - 8]));
            const float Ab  = fmaxf(__expf(dv * A_s), EPSF);
            prevA = Acum;
            Acum  = prevA * Ab;
            wc    = fmaf(dv * Bf[k] * xcv, frcp(fmaxf(prevA, EPSF)), wc);
        }
        xcp += 16; p0p += 16; Bp += 16;
    }
    const size_t base = ((size_t)c * NCH + ch) * 16 + s;
    Pbuf[base] = Acum;
    qbuf[base] = prevA * wc;
}

__global__ __launch_bounds__(256) void combine_k(const float* __restrict__ Pbuf,
                                                 const float* __restrict__ qbuf,
                                                 float* __restrict__ hbuf) {
    const int i = blockIdx.x * 256 + threadIdx.x;
    float h = 0.f;
    #pragma unroll
    for (int c = 0; c < NCHUNK; ++c) {
        const size_t idx = (size_t)c * (NCH * 16) + i;
        hbuf[idx] = h;                               // state ENTERING chunk c
        h = fmaf(Pbuf[idx], h, qbuf[idx]);
    }
}

// ---------------------------------------------------------------------------
// Scan pass 2: replay + output.  red[16 gi][8 k][20 sigma] = 10752 B ->
// 8 blocks/CU (wave-limited; no grid tail).  Group stride 168 == 8 (mod 32)
// -> uniform 2-way bank aliasing on writes (free).  Per 8 steps: lane s sums
// 8 states of row (s&7) (2 ds_read_b128), one xor-8 swizzle combines halves,
// lanes s<8 store.  gz pre-gated (silu in gemm1) -> no exp in epilogue.
// ---------------------------------------------------------------------------
__global__ __launch_bounds__(256) void scan_p2(const ushort_t* __restrict__ xc_T,
                                               const float* __restrict__ xp_T,
                                               const ushort_t* __restrict__ gzT,
                                               const float* __restrict__ dt_w,
                                               const float* __restrict__ dt_b,
                                               const float* __restrict__ A_log,
                                               const float* __restrict__ D_par,
                                               const float* __restrict__ hbuf,
                                               ushort_t* __restrict__ G) {
    __shared__ alignas(16) float red[16 * 168];
    const int tid = threadIdx.x;
    const int s   = tid & 15;
    const int gi  = tid >> 4;
    const int ch  = blockIdx.x * 16 + gi;
    const int c   = blockIdx.y;
    const int b   = ch >> 11;
    const int d   = ch & (D_INNER - 1);
    const float A_s   = -__expf(A_log[s]);
    const float dtw   = dt_w[d];
    const float dtb   = dt_b[d];
    const float dterm = (s == 0) ? D_par[d] : 0.f;   // folds D*x into the sigma-sum
    const float h0    = hbuf[((size_t)c * NCH + ch) * 16 + s];
    const int rowbase = b * SEQLEN + c * CHUNKT;
    const ushort_t* xcp = xc_T + (size_t)ch * SEQLEN + c * CHUNKT;
    const float*    p0p = xp_T + rowbase;
    const float*    Bp  = xp_T + (size_t)(1 + s) * NROW + rowbase;
    const float*    Cp  = xp_T + (size_t)(17 + s) * NROW + rowbase;
    const ushort_t* gzp = gzT + (size_t)ch * SEQLEN + c * CHUNKT;
    ushort_t*       Gcol = G + (size_t)rowbase * D_INNER + d;
    float* redw = &red[gi * 168];
    const int rbase = (s & 7) * 20 + (s >> 3) * 8;   // 16B-aligned read base
    float Acum = 1.f, wc = 0.f;
    for (int T = 0; T < CHUNKT; T += 16) {
        const float dv_s = softplus_f(fmaf(p0p[s], dtw, dtb));
        float dvb[16];
        BCAST_ALL(dvb, dv_s)
        float Bf[16], Cf[16];
        #pragma unroll
        for (int q = 0; q < 4; ++q) {
            ((f32x4*)Bf)[q] = ((const f32x4*)Bp)[q];
            ((f32x4*)Cf)[q] = ((const f32x4*)Cp)[q];
        }
        const short8 xv0 = ((const short8*)xcp)[0];
        const short8 xv1 = ((const short8*)xcp)[1];
        const float zval = bf2f(gzp[s]);             // gz(T+s), coalesced 2B/lane
        #pragma unroll
        for (int h = 0; h < 2; ++h) {
            #pragma unroll
            for (int k8 = 0; k8 < 8; ++k8) {
                const int k = h * 8 + k8;
                const float dv  = dvb[k];
                const float xcv = bf2f((ushort_t)(k < 8 ? xv0[k] : xv1[k - 8]));
                const float Ab  = fmaxf(__expf(dv * A_s), EPSF);
                const float prevA = Acum;
                Acum = prevA * Ab;
                wc   = fmaf(dv * Bf[k] * xcv, frcp(fmaxf(prevA, EPSF)), wc);
                const float hh = fmaf(prevA, wc, h0 * Acum);
                redw[k8 * 20 + s] = fmaf(dterm, xcv, Cf[k] * hh);
            }
            // lane s: sum 8 states of timestep (s&7), half (s>>3)
            const float* rr = &redw[rbase];
            const f32x4 r0 = ((const f32x4*)rr)[0];
            const f32x4 r1 = ((const f32x4*)rr)[1];
            float y = ((r0[0] + r0[1]) + (r0[2] + r0[3])) +
                      ((r1[0] + r1[1]) + (r1[2] + r1[3]));
            y += swz_xor8(y);                        // full 16-state sum
            const float zz = h ? swz_xor8(zval) : zval;
            if (s < 8) {
                Gcol[(size_t)(T + h * 8 + s) * D_INNER] = f2bf(y * zz);
            }
        }
        xcp += 16; p0p += 16; Bp += 16; Cp += 16; gzp += 16;
    }
}

// ---------------------------------------------------------------------------
// gemm2 (m97-style, unchanged): out = G @ w_out^T.
// ---------------------------------------------------------------------------
template<int K, typename TC>
__global__ __launch_bounds__(256) void gemm_lds(const ushort_t* __restrict__ A,
                                                const ushort_t* __restrict__ B,
                                                TC* __restrict__ C, int N) {
    __shared__ alignas(16) ushort_t As[128 * 32];
    __shared__ alignas(16) ushort_t Bs[128 * 32];
    const int tid  = threadIdx.x;
    const int wave = tid >> 6, lane = tid & 63;
    const int wm = (wave >> 1) * 64, wn = (wave & 1) * 64;
    const int row0 = blockIdx.y * 128, col0 = blockIdx.x * 128;
    f32x4 acc[4][4] = {};
    const int srow = wave * 32 + (lane >> 2);
    const int scol = (lane & 3) * 8;
    const ushort_t* Ag = A + (size_t)(row0 + srow) * K + scol;
    const ushort_t* Bg = B + (size_t)(col0 + srow) * K + scol;
    ushort_t* Al = As + (wave * 32) * 32;
    ushort_t* Bl = Bs + (wave * 32) * 32;
    const int fr = lane & 15;
    const int fk = (lane >> 4) * 8;
    for (int k0 = 0; k0 < K; k0 += 32) {
        async_ld16(Ag,          Al);
        async_ld16(Ag + 16 * K, Al + 16 * 32);
        async_ld16(Bg,          Bl);
        async_ld16(Bg + 16 * K, Bl + 16 * 32);
        __syncthreads();
        short8 af[4], bfr[4];
        #pragma unroll
        for (int i = 0; i < 4; ++i) {
            af[i]  = *(const short8*)&As[(wm + i * 16 + fr) * 32 + fk];
            bfr[i] = *(const short8*)&Bs[(wn + i * 16 + fr) * 32 + fk];
        }
        #pragma unroll
        for (int i = 0; i < 4; ++i)
            #pragma unroll
            for (int j = 0; j < 4; ++j)
                acc[i][j] = __builtin_amdgcn_mfma_f32_16x16x32_bf16(af[i], bfr[j], acc[i][j], 0, 0, 0);
        __syncthreads();
        Ag += 32; Bg += 32;
    }
    const int quad = lane >> 4;
    #pragma unroll
    for (int i = 0; i < 4; ++i)
        #pragma unroll
        for (int j = 0; j < 4; ++j)
            #pragma unroll
            for (int r = 0; r < 4; ++r) {
                int row = row0 + wm + i * 16 + quad * 4 + r;
                int col = col0 + wn + j * 16 + fr;
                st1(&C[(size_t)row * N + col], acc[i][j][r]);
            }
}

// ---------------------------------------------------------------------------
extern "C" void kernel_launch(void* const* d_in, const int* in_sizes, int n_in,
                              void* d_out, int out_size, void* d_ws, size_t ws_size,
                              hipStream_t stream) {
    const float* x     = (const float*)d_in[0];
    const float* cw    = (const float*)d_in[2];
    const float* cb    = (const float*)d_in[3];
    const float* w_xp  = (const float*)d_in[4];
    const float* dtw   = (const float*)d_in[5];
    const float* dtb   = (const float*)d_in[6];
    const float* alog  = (const float*)d_in[7];
    const float* dpar  = (const float*)d_in[8];
    const float* w_in  = (const float*)d_in[1];
    const float* w_out = (const float*)d_in[9];
    float* out = (float*)d_out;

    char* ws = (char*)d_ws;
    const size_t MB = 1024ull * 1024ull;
    // Live-range map (total 71 MiB, same as passing round 7):
    ushort_t* xi   = (ushort_t*)ws;                  //  0-16: xi bf16, dead after conv_t
    ushort_t* gzT  = (ushort_t*)(ws + 16 * MB);      // 16-32: silu(z) time-major, live to p2
    ushort_t* xc   = (ushort_t*)(ws + 32 * MB);      // 32-48: xc row-major; G overlays in p2
    float*    xp_T = (float*)   (ws + 48 * MB);      // 48-48.6 [33, NROW]
    float*    Pbuf = (float*)   (ws + 49 * MB);      // 49-51
    float*    qbuf = (float*)   (ws + 51 * MB);      // 51-53
    float*    hbuf = (float*)   (ws + 53 * MB);      // 53-55
    ushort_t* xcT  = (ushort_t*)(ws + 55 * MB);      // 55-71 [NCH, SEQLEN]
    // Overlays: xb/winb live only during gemm1 (xc region unwritten until conv_t);
    // wob written after combine over dead Pbuf/qbuf.
    ushort_t* xb   = (ushort_t*)(ws + 32 * MB);      // 32-40
    ushort_t* winb = (ushort_t*)(ws + 40 * MB);      // 40-48
    ushort_t* wob  = (ushort_t*)(ws + 49 * MB);      // 49-53
    ushort_t* G    = xc;

    // 0) bf16 conversions for gemm1
    hipLaunchKernelGGL(cvt_bf16_k, dim3(NROW * D_MODEL / 2048), dim3(256), 0, stream, x, xb);
    hipLaunchKernelGGL(cvt_bf16_k, dim3(2 * D_INNER * D_MODEL / 2048), dim3(256), 0, stream, w_in, winb);
    // 1) xz GEMM, split epilogue: xi row-major + gz_T = silu(z) time-major
    hipLaunchKernelGGL(gemm1_k, dim3(2 * D_INNER / 128, NROW / 128), dim3(256), 0, stream,
                       xb, winb, xi, gzT);
    // 2) fused conv+silu+transpose: xc (row-major) + xc_T (time-major)
    hipLaunchKernelGGL(conv_t_k, dim3(SEQLEN / 64, D_INNER / 64, BATCH), dim3(256), 0, stream,
                       xi, cw, cb, xc, xcT);
    // 3) xp_T = (xc @ x_proj_w^T)^T
    hipLaunchKernelGGL(xproj_k, dim3(NROW / 4), dim3(256), 0, stream, xc, w_xp, xp_T);
    // 4a) per-chunk (P,q)
    hipLaunchKernelGGL(scan_p1, dim3(NCH / 16, NCHUNK), dim3(256), 0, stream,
                       xcT, xp_T, dtw, dtb, alog, Pbuf, qbuf);
    // 4b) chunk chain -> h0 per chunk
    hipLaunchKernelGGL(combine_k, dim3(NCH * 16 / 256), dim3(256), 0, stream,
                       Pbuf, qbuf, hbuf);
    // 4c) convert w_out (into dead Pbuf/qbuf region)
    hipLaunchKernelGGL(cvt_bf16_k, dim3(D_MODEL * D_INNER / 2048), dim3(256), 0, stream, w_out, wob);
    // 4d) replay with h0, emit G = (C.h + D*x)*gz  (in place over xc)
    hipLaunchKernelGGL(scan_p2, dim3(NCH / 16, NCHUNK), dim3(256), 0, stream,
                       xcT, xp_T, gzT, dtw, dtb, alog, dpar, hbuf, G);
    // 5) out = G @ out_proj_w^T  (M=4096, N=1024, K=2048)
    hipLaunchKernelGGL((gemm_lds<D_INNER, float>),
                       dim3(D_MODEL / 128, NROW / 128), dim3(256), 0, stream,
                       G, wob, out, D_MODEL);
    (void)in_sizes; (void)n_in; (void)out_size; (void)ws_size;
}